// Round 4
// baseline (5939.219 us; speedup 1.0000x reference)
//
#include <hip/hip_runtime.h>
#include <hip/hip_bf16.h>
#include <math.h>

#define DD   43      // hidden size
#define RR   172     // 4*DD gate rows
#define TT   2048
#define BB   256
#define FEAT 8
#define NH1  30
#define NH2  20

using bf16 = __hip_bfloat16;

__device__ __forceinline__ float ldv(const float* p)  { return *p; }
__device__ __forceinline__ float ldv(const bf16* p)   { return __bfloat162float(*p); }
__device__ __forceinline__ void  stv(float* p, float v) { *p = v; }
__device__ __forceinline__ void  stv(bf16* p,  float v) { *p = __float2bfloat16(v); }

__device__ __forceinline__ float sig_(float x) {
    return 1.0f / (1.0f + __expf(-x));
}
__device__ __forceinline__ float tanh_(float x) {
    float ax = fabsf(x);
    float e  = __expf(-2.0f * ax);
    float t  = (1.0f - e) / (1.0f + e);
    return x < 0.0f ? -t : t;
}

// ---- prep: fold input projection into layer-1 weights; combine biases ----
__global__ void prep_kernel(const float* __restrict__ wp, const float* __restrict__ bp,
                            const float* __restrict__ w_ih1f, const float* __restrict__ b_ih1f, const float* __restrict__ b_hh1f,
                            const float* __restrict__ w_ih1b, const float* __restrict__ b_ih1b, const float* __restrict__ b_hh1b,
                            const float* __restrict__ b_ih2f, const float* __restrict__ b_hh2f,
                            const float* __restrict__ b_ih2b, const float* __restrict__ b_hh2b,
                            float* __restrict__ w_eff1, float* __restrict__ b_eff1,
                            float* __restrict__ b_eff2) {
    int tid = blockIdx.x * blockDim.x + threadIdx.x;
    if (tid < 2 * RR) {
        int dir = tid / RR, r = tid % RR;
        const float* w_ih = dir ? w_ih1b : w_ih1f;
        const float* bi   = dir ? b_ih1b : b_ih1f;
        const float* bh   = dir ? b_hh1b : b_hh1f;
        const float* row  = w_ih + (long)r * DD;
        float acc[FEAT];
#pragma unroll
        for (int k = 0; k < FEAT; ++k) acc[k] = 0.0f;
        float bacc = bi[r] + bh[r];
        for (int d = 0; d < DD; ++d) {
            float w = row[d];
            bacc = fmaf(w, bp[d], bacc);
#pragma unroll
            for (int k = 0; k < FEAT; ++k) acc[k] = fmaf(w, wp[d * FEAT + k], acc[k]);
        }
#pragma unroll
        for (int k = 0; k < FEAT; ++k) w_eff1[(long)tid * FEAT + k] = acc[k];
        b_eff1[tid] = bacc;
    } else if (tid < 4 * RR) {
        int j = tid - 2 * RR;
        int dir = j / RR, r = j % RR;
        b_eff2[j] = dir ? (b_ih2b[r] + b_hh2b[r]) : (b_ih2f[r] + b_hh2f[r]);
    }
}

// ---- one bidirectional LSTM layer: one block per (dir,batch) chain ----
// 2 threads per gate-row (344 workers of 384): each holds HALF of the padded
// concatenated [x;h] weight vector in VGPRs; combine via __shfl_xor(z,1).
// amdgpu_waves_per_eu(3,3) pins the allocator budget to 512/3 = 170 VGPRs so
// the weight arrays actually STAY in registers (round-3 failure: allocator
// targeted 8 waves/EU -> 52 VGPRs -> weights spilled to scratch).
template <int KI, typename TIN, typename TOUT>
__global__ __launch_bounds__(384)
__attribute__((amdgpu_waves_per_eu(3, 3)))
void lstm_kernel(
        const TIN* __restrict__ in,        // [B][T][KI]
        const float* __restrict__ w_ih_f,  // [RR][KI]
        const float* __restrict__ w_hh_f,  // [RR][DD]
        const float* __restrict__ bias_f,  // [RR] (combined)
        const float* __restrict__ w_ih_b,
        const float* __restrict__ w_hh_b,
        const float* __restrict__ bias_b,
        TOUT* __restrict__ out)            // [B][T][2*DD]
{
    constexpr int K    = KI + DD;          // concatenated [x;h] length
    constexpr int K4   = (K + 3) / 4;      // float4 groups
    constexpr int H0   = (K4 + 1) / 2;     // groups for even thread (>= odd's)
    constexpr int KPAD = 8 * H0;           // padded buffer length (floats)

    const int bid = blockIdx.x;
    const int dir = bid & 1;
    const int b   = bid >> 1;
    const int tid = threadIdx.x;

    const float* w_ih = dir ? w_ih_b : w_ih_f;
    const float* w_hh = dir ? w_hh_b : w_hh_f;
    const float* bias = dir ? bias_b : bias_f;

    __shared__ __align__(16) float sbuf[2][KPAD];  // [0..KI)=x_t, [KI..K)=h, rest 0
    __shared__ float zbuf[RR];

    const int r  = tid >> 1;        // gate row
    const int hf = tid & 1;         // which half of K
    const int g0 = hf ? H0 : 0;
    const int gN = hf ? (K4 - H0) : H0;

    float w[4 * H0];
    float bsum = 0.0f, c = 0.0f;
    if (tid < 2 * RR) {
#pragma unroll
        for (int g = 0; g < H0; ++g) {
#pragma unroll
            for (int j = 0; j < 4; ++j) {
                int k = 4 * (g0 + g) + j;
                float v = 0.0f;
                if (g < gN && k < K)
                    v = (k < KI) ? w_ih[(long)r * KI + k]
                                 : w_hh[(long)r * DD + (k - KI)];
                w[4 * g + j] = v;
            }
        }
        if (hf == 0) bsum = bias[r];
    }
    // zero h region (initial h=0) and padding, both buffers
    for (int k = KI + tid; k < KPAD; k += 384) {
        sbuf[0][k] = 0.0f;
        sbuf[1][k] = 0.0f;
    }

    const long t0  = dir ? (TT - 1) : 0;
    const int  stp = dir ? -1 : 1;

    float xnext = 0.0f;
    if (tid < KI) xnext = ldv(in + ((long)b * TT + t0) * KI + tid);

    TOUT* outp = out + (long)b * TT * (2 * DD) + dir * DD;

    __syncthreads();

    long t = t0;
    for (int s = 0; s < TT; ++s) {
        const int cur = s & 1, nxt = cur ^ 1;
        if (tid < KI) sbuf[cur][tid] = xnext;
        __syncthreads();

        // prefetch next timestep's x (latency hidden under this step)
        const long tn = t + stp;
        if (s + 1 < TT && tid < KI) xnext = ldv(in + ((long)b * TT + tn) * KI + tid);

        if (tid < 2 * RR) {
            const float4* sv = reinterpret_cast<const float4*>(&sbuf[cur][0]) + g0;
            float a0 = bsum, a1 = 0.0f, a2 = 0.0f, a3 = 0.0f;
#pragma unroll
            for (int g = 0; g < H0; ++g) {
                float4 xv = sv[g];
                a0 = fmaf(w[4 * g + 0], xv.x, a0);
                a1 = fmaf(w[4 * g + 1], xv.y, a1);
                a2 = fmaf(w[4 * g + 2], xv.z, a2);
                a3 = fmaf(w[4 * g + 3], xv.w, a3);
            }
            float z = (a0 + a1) + (a2 + a3);
            z += __shfl_xor(z, 1);
            if (hf == 0) {
                // gate order i,f,g,o: rows [2DD,3DD) use tanh, rest sigmoid
                float act = (r >= 2 * DD && r < 3 * DD) ? tanh_(z) : sig_(z);
                zbuf[r] = act;
            }
        }
        __syncthreads();

        if (tid < DD) {
            float ig = zbuf[tid];
            float fg = zbuf[tid + DD];
            float gg = zbuf[tid + 2 * DD];
            float og = zbuf[tid + 3 * DD];
            c = fmaf(fg, c, ig * gg);
            float h = og * tanh_(c);
            sbuf[nxt][KI + tid] = h;           // h for next step
            stv(&outp[t * (2 * DD) + tid], h);
        }
        t = tn;
    }
}

// ---- dense head: per (b,t): 86 -> 30 -> 20 -> 1 ----
template <typename TIN>
__global__ void head_kernel(const TIN* __restrict__ h2,   // [BT][2*DD]
                            const float* __restrict__ w1, const float* __restrict__ b1,
                            const float* __restrict__ w2, const float* __restrict__ b2,
                            const float* __restrict__ w3, const float* __restrict__ b3,
                            float* __restrict__ outp) {
    long bt = (long)blockIdx.x * blockDim.x + threadIdx.x;
    if (bt >= (long)BB * TT) return;
    float v[2 * DD];
    const TIN* src = h2 + bt * (2 * DD);
#pragma unroll
    for (int k = 0; k < 2 * DD; ++k) v[k] = ldv(&src[k]);

    float m1[NH1];
#pragma unroll
    for (int j = 0; j < NH1; ++j) {
        float a = b1[j];
        const float* w = w1 + j * (2 * DD);
#pragma unroll
        for (int k = 0; k < 2 * DD; ++k) a = fmaf(w[k], v[k], a);
        m1[j] = fmaxf(a, 0.0f);
    }
    float m2[NH2];
#pragma unroll
    for (int j = 0; j < NH2; ++j) {
        float a = b2[j];
        const float* w = w2 + j * NH1;
#pragma unroll
        for (int k = 0; k < NH1; ++k) a = fmaf(w[k], m1[k], a);
        m2[j] = fmaxf(a, 0.0f);
    }
    float a = b3[0];
#pragma unroll
    for (int k = 0; k < NH2; ++k) a = fmaf(w3[k], m2[k], a);
    outp[bt] = a;
}

extern "C" void kernel_launch(void* const* d_in, const int* in_sizes, int n_in,
                              void* d_out, int out_size, void* d_ws, size_t ws_size,
                              hipStream_t stream) {
    const float* x      = (const float*)d_in[0];
    const float* w_proj = (const float*)d_in[1];
    const float* b_proj = (const float*)d_in[2];
    const float* w_ih1f = (const float*)d_in[3];
    const float* w_hh1f = (const float*)d_in[4];
    const float* b_ih1f = (const float*)d_in[5];
    const float* b_hh1f = (const float*)d_in[6];
    const float* w_ih1b = (const float*)d_in[7];
    const float* w_hh1b = (const float*)d_in[8];
    const float* b_ih1b = (const float*)d_in[9];
    const float* b_hh1b = (const float*)d_in[10];
    const float* w_ih2f = (const float*)d_in[11];
    const float* w_hh2f = (const float*)d_in[12];
    const float* b_ih2f = (const float*)d_in[13];
    const float* b_hh2f = (const float*)d_in[14];
    const float* w_ih2b = (const float*)d_in[15];
    const float* w_hh2b = (const float*)d_in[16];
    const float* b_ih2b = (const float*)d_in[17];
    const float* b_hh2b = (const float*)d_in[18];
    const float* w_d1   = (const float*)d_in[19];
    const float* b_d1   = (const float*)d_in[20];
    const float* w_d2   = (const float*)d_in[21];
    const float* b_d2   = (const float*)d_in[22];
    const float* w_out  = (const float*)d_in[23];
    const float* b_out  = (const float*)d_in[24];
    (void)in_sizes; (void)n_in; (void)out_size;

    // --- workspace layout ---
    float* w_eff1 = (float*)d_ws;
    float* b_eff1 = w_eff1 + 2 * RR * FEAT;
    float* b_eff2 = b_eff1 + 2 * RR;
    char*  big    = (char*)d_ws + 16384;
    size_t avail  = ws_size > 16384 ? ws_size - 16384 : 0;

    const size_t n1 = (size_t)BB * TT * 2 * DD;        // elems of out1/out2
    const size_t f1 = n1 * sizeof(float);              // 180.4 MB
    const size_t h1 = n1 * sizeof(bf16);               // 90.2 MB

    int tier;
    if      (avail >= f1 + f1) tier = 0;
    else if (avail >= f1 + h1) tier = 1;
    else                       tier = 2;

    prep_kernel<<<(4 * RR + 191) / 192, 192, 0, stream>>>(
        w_proj, b_proj,
        w_ih1f, b_ih1f, b_hh1f, w_ih1b, b_ih1b, b_hh1b,
        b_ih2f, b_hh2f, b_ih2b, b_hh2b,
        w_eff1, b_eff1, b_eff2);

    const float* weff_f = w_eff1;
    const float* weff_b = w_eff1 + (size_t)RR * FEAT;
    const float* be1_f  = b_eff1;
    const float* be1_b  = b_eff1 + RR;
    const float* be2_f  = b_eff2;
    const float* be2_b  = b_eff2 + RR;
    const int head_blocks = (int)(((long)BB * TT + 255) / 256);

    if (tier == 0) {
        float* out1 = (float*)big;
        float* out2 = (float*)(big + f1);
        lstm_kernel<FEAT, float, float><<<2 * BB, 384, 0, stream>>>(
            x, weff_f, w_hh1f, be1_f, weff_b, w_hh1b, be1_b, out1);
        lstm_kernel<2 * DD, float, float><<<2 * BB, 384, 0, stream>>>(
            out1, w_ih2f, w_hh2f, be2_f, w_ih2b, w_hh2b, be2_b, out2);
        head_kernel<float><<<head_blocks, 256, 0, stream>>>(
            out2, w_d1, b_d1, w_d2, b_d2, w_out, b_out, (float*)d_out);
    } else if (tier == 1) {
        float* out1 = (float*)big;
        bf16*  out2 = (bf16*)(big + f1);
        lstm_kernel<FEAT, float, float><<<2 * BB, 384, 0, stream>>>(
            x, weff_f, w_hh1f, be1_f, weff_b, w_hh1b, be1_b, out1);
        lstm_kernel<2 * DD, float, bf16><<<2 * BB, 384, 0, stream>>>(
            out1, w_ih2f, w_hh2f, be2_f, w_ih2b, w_hh2b, be2_b, out2);
        head_kernel<bf16><<<head_blocks, 256, 0, stream>>>(
            out2, w_d1, b_d1, w_d2, b_d2, w_out, b_out, (float*)d_out);
    } else {
        bf16* out1 = (bf16*)big;
        bf16* out2 = (bf16*)(big + h1);
        lstm_kernel<FEAT, float, bf16><<<2 * BB, 384, 0, stream>>>(
            x, weff_f, w_hh1f, be1_f, weff_b, w_hh1b, be1_b, out1);
        lstm_kernel<2 * DD, bf16, bf16><<<2 * BB, 384, 0, stream>>>(
            out1, w_ih2f, w_hh2f, be2_f, w_ih2b, w_hh2b, be2_b, out2);
        head_kernel<bf16><<<head_blocks, 256, 0, stream>>>(
            out2, w_d1, b_d1, w_d2, b_d2, w_out, b_out, (float*)d_out);
    }
}

// Round 5
// 5276.823 us; speedup vs baseline: 1.1255x; 1.1255x over previous
//
#include <hip/hip_runtime.h>
#include <hip/hip_bf16.h>
#include <math.h>

#define DD   43      // hidden size
#define RR   172     // 4*DD gate rows
#define NPAD 176     // padded gate rows (11 n-tiles of 16)
#define TT   2048
#define BB   256
#define FEAT 8
#define MB   16      // batches per block (MFMA M)
#define NH1  30
#define NH2  20

using bf16 = __hip_bfloat16;
typedef __attribute__((ext_vector_type(8))) short bf16x8;   // MFMA A/B frag (8 bf16)
typedef __attribute__((ext_vector_type(4))) float f32x4;    // MFMA C/D frag

__device__ __forceinline__ float ldv(const float* p)  { return *p; }
__device__ __forceinline__ float ldv(const bf16* p)   { return __bfloat162float(*p); }
__device__ __forceinline__ void  stv(float* p, float v) { *p = v; }
__device__ __forceinline__ void  stv(bf16* p,  float v) { *p = __float2bfloat16(v); }

__device__ __forceinline__ short f2b(float f) {
    bf16 h = __float2bfloat16(f);
    return *reinterpret_cast<short*>(&h);
}
__device__ __forceinline__ float sig_(float x) { return 1.0f / (1.0f + __expf(-x)); }
__device__ __forceinline__ float tanh_(float x) {
    float ax = fabsf(x);
    float e  = __expf(-2.0f * ax);
    float t  = (1.0f - e) / (1.0f + e);
    return x < 0.0f ? -t : t;
}

// ---------------- prep: build padded bf16 weight blocks + combined fp32 biases ----
// W1 [2][NPAD][96]  : cols 0..7   = w_eff1 (= w_ih1 @ w_proj, proj folded), 8..31 = 0,
//                     cols 32..74 = w_hh1, 75..95 = 0. Rows >= 172 all zero.
// W2 [2][NPAD][160] : cols 0..85  = w_ih2, 86..95 = 0, 96..138 = w_hh2, 139..159 = 0.
// bias1 [2][NPAD]   : b_ih1 + b_hh1 + w_ih1 @ b_proj (proj bias folded), pad 0.
// bias2 [2][NPAD]   : b_ih2 + b_hh2, pad 0.
__global__ void prep_kernel(
    const float* __restrict__ wp, const float* __restrict__ bp,
    const float* __restrict__ w_ih1f, const float* __restrict__ w_hh1f,
    const float* __restrict__ b_ih1f, const float* __restrict__ b_hh1f,
    const float* __restrict__ w_ih1b, const float* __restrict__ w_hh1b,
    const float* __restrict__ b_ih1b, const float* __restrict__ b_hh1b,
    const float* __restrict__ w_ih2f, const float* __restrict__ w_hh2f,
    const float* __restrict__ b_ih2f, const float* __restrict__ b_hh2f,
    const float* __restrict__ w_ih2b, const float* __restrict__ w_hh2b,
    const float* __restrict__ b_ih2b, const float* __restrict__ b_hh2b,
    short* __restrict__ W1, short* __restrict__ W2,
    float* __restrict__ bias1, float* __restrict__ bias2)
{
    const int S1 = 2 * NPAD * 96, S2 = 2 * NPAD * 160, S3 = 2 * NPAD;
    int idx = blockIdx.x * blockDim.x + threadIdx.x;
    if (idx < S1) {
        int dir = idx / (NPAD * 96), rem = idx % (NPAD * 96);
        int n = rem / 96, k = rem % 96;
        const float* wih = dir ? w_ih1b : w_ih1f;
        const float* whh = dir ? w_hh1b : w_hh1f;
        float v = 0.0f;
        if (n < RR) {
            if (k < FEAT) {
                for (int d = 0; d < DD; ++d) v = fmaf(wih[n * DD + d], wp[d * FEAT + k], v);
            } else if (k >= 32 && k < 32 + DD) {
                v = whh[n * DD + (k - 32)];
            }
        }
        W1[idx] = f2b(v);
    } else if (idx < S1 + S2) {
        int j = idx - S1;
        int dir = j / (NPAD * 160), rem = j % (NPAD * 160);
        int n = rem / 160, k = rem % 160;
        const float* wih = dir ? w_ih2b : w_ih2f;
        const float* whh = dir ? w_hh2b : w_hh2f;
        float v = 0.0f;
        if (n < RR) {
            if (k < 2 * DD)                 v = wih[n * (2 * DD) + k];
            else if (k >= 96 && k < 96 + DD) v = whh[n * DD + (k - 96)];
        }
        W2[j] = f2b(v);
    } else if (idx < S1 + S2 + S3) {
        int j = idx - S1 - S2;
        int dir = j / NPAD, n = j % NPAD;
        float v = 0.0f;
        if (n < RR) {
            const float* wih = dir ? w_ih1b : w_ih1f;
            const float* bi  = dir ? b_ih1b : b_ih1f;
            const float* bh  = dir ? b_hh1b : b_hh1f;
            v = bi[n] + bh[n];
            for (int d = 0; d < DD; ++d) v = fmaf(wih[n * DD + d], bp[d], v);
        }
        bias1[j] = v;
    } else if (idx < S1 + S2 + 2 * S3) {
        int j = idx - S1 - S2 - S3;
        int dir = j / NPAD, n = j % NPAD;
        float v = 0.0f;
        if (n < RR) {
            const float* bi = dir ? b_ih2b : b_ih2f;
            const float* bh = dir ? b_hh2b : b_hh2f;
            v = bi[n] + bh[n];
        }
        bias2[j] = v;
    }
}

// ---------------- MFMA-based BiLSTM layer ----------------
// One block per (dir, 16-batch tile): grid = 2 * (BB/MB) = 32 blocks, 512 threads (8 waves).
// Weights live in VGPRs as MFMA B-fragments (loaded once). Per step:
//   z[16 batches][176 rows] = bias + [x;h]_bf16 @ W^T  via 16x16x32 MFMA,
//   activations -> zact (LDS), then c/h update by (batch,dd)-mapped threads.
// KSX = # of K=32 steps for the x part (1 for layer1 pad(8)->32, 3 for layer2 pad(86)->96).
template <int KSX, bool XRAW>
__global__ __launch_bounds__(512, 2) void lstm_mfma(
    const void*  __restrict__ in_,     // XRAW ? fp32 [B][T][8] : bf16 [B][T][86]
    const short* __restrict__ Wb,      // [2][NPAD][KPAD] bf16 bits
    const float* __restrict__ bias,    // [2][NPAD]
    bf16* __restrict__ out)            // [B][T][86]; this kernel fills cols dir*43..dir*43+43
{
    constexpr int KS   = KSX + 2;      // + 2 K-steps for h (pad 43 -> 64)
    constexpr int KPAD = KS * 32;

    const int dir   = blockIdx.x & 1;
    const int btile = blockIdx.x >> 1;
    const int tid   = threadIdx.x;
    const int lane  = tid & 63;
    const int wv    = tid >> 6;        // wave 0..7
    const int ln15  = lane & 15;
    const int lg    = lane >> 4;       // 0..3

    __shared__ __align__(16) short hbuf[MB][72];   // bf16 h, cols 43..63 zero (K pad), 64..71 row pad
    __shared__ float zact[MB][177];                // activated gates (stride 177 kills bank conflicts)

    // n-tiles: wave w owns tile w, and tile 8+w when w < 3  (11 tiles total)
    const int nt = (wv < 3) ? 2 : 1;

    bf16x8 wfrag[2][KS];
    float  bv[2];
    bool   isg[2];
    {
        const short* Wd = Wb + (size_t)dir * NPAD * KPAD;
#pragma unroll
        for (int ti = 0; ti < 2; ++ti) {
            int tile = ti ? (8 + wv) : wv;
            int n = tile * 16 + ln15;
            isg[ti] = (n >= 2 * DD && n < 3 * DD);   // tanh gate rows
            if (ti < nt) {
#pragma unroll
                for (int ks = 0; ks < KS; ++ks)
                    wfrag[ti][ks] = *reinterpret_cast<const bf16x8*>(
                        Wd + (size_t)n * KPAD + ks * 32 + lg * 8);
                bv[ti] = bias[dir * NPAD + n];
            } else {
#pragma unroll
                for (int ks = 0; ks < KS; ++ks) wfrag[ti][ks] = bf16x8(0);
                bv[ti] = 0.0f;
            }
        }
    }

    // phase-B (state update) mapping: 688 (b,dd) pairs over 512 threads, 2 slots
    const int p0 = tid;
    const int b0 = p0 / DD, d0 = p0 % DD;
    const int p1 = tid + 512;
    const bool has1 = (p1 < MB * DD);
    const int b1 = has1 ? p1 / DD : 0, d1 = has1 ? p1 % DD : 0;
    float c0 = 0.0f, c1 = 0.0f;

    for (int i = tid; i < MB * 72; i += 512) ((short*)hbuf)[i] = 0;

    const long t00   = dir ? (TT - 1) : 0;
    const int  stp   = dir ? -1 : 1;
    const long bbase = (long)(btile * MB + ln15);   // batch this lane represents in A-frags

    union U { unsigned u[4]; bf16x8 v; };
    U xc[KSX], xn[KSX];

    auto load_x = [&](long t, U (&xf)[KSX]) {
        if constexpr (XRAW) {
            if (lg == 0) {
                const float* xp = (const float*)in_ + (bbase * TT + t) * FEAT;
                float4 v0 = *reinterpret_cast<const float4*>(xp);
                float4 v1 = *reinterpret_cast<const float4*>(xp + 4);
                xf[0].u[0] = ((unsigned)(unsigned short)f2b(v0.y) << 16) | (unsigned short)f2b(v0.x);
                xf[0].u[1] = ((unsigned)(unsigned short)f2b(v0.w) << 16) | (unsigned short)f2b(v0.z);
                xf[0].u[2] = ((unsigned)(unsigned short)f2b(v1.y) << 16) | (unsigned short)f2b(v1.x);
                xf[0].u[3] = ((unsigned)(unsigned short)f2b(v1.w) << 16) | (unsigned short)f2b(v1.z);
            } else {
#pragma unroll
                for (int j = 0; j < 4; ++j) xf[0].u[j] = 0u;
            }
        } else {
            const short* xp = (const short*)in_ + (bbase * TT + t) * (2 * DD);
#pragma unroll
            for (int ks = 0; ks < KSX; ++ks) {
                int k0 = ks * 32 + lg * 8;
#pragma unroll
                for (int j = 0; j < 4; ++j) {
                    int k = k0 + 2 * j;
                    xf[ks].u[j] = (k < 2 * DD) ? *reinterpret_cast<const unsigned*>(xp + k) : 0u;
                }
            }
        }
    };

    load_x(t00, xc);
    __syncthreads();    // hbuf zeros visible

    long t = t00;
    for (int s = 0; s < TT; ++s) {
        // ---- phase A: gate GEMM + activations ----
        bf16x8 ah0 = *reinterpret_cast<const bf16x8*>(&hbuf[ln15][lg * 8]);
        bf16x8 ah1 = *reinterpret_cast<const bf16x8*>(&hbuf[ln15][32 + lg * 8]);
        if (s + 1 < TT) load_x(t + stp, xn);   // prefetch next x under this step

        f32x4 acc0 = {bv[0], bv[0], bv[0], bv[0]};
#pragma unroll
        for (int ks = 0; ks < KSX; ++ks)
            acc0 = __builtin_amdgcn_mfma_f32_16x16x32_bf16(xc[ks].v, wfrag[0][ks], acc0, 0, 0, 0);
        acc0 = __builtin_amdgcn_mfma_f32_16x16x32_bf16(ah0, wfrag[0][KSX],     acc0, 0, 0, 0);
        acc0 = __builtin_amdgcn_mfma_f32_16x16x32_bf16(ah1, wfrag[0][KSX + 1], acc0, 0, 0, 0);

        f32x4 acc1 = {bv[1], bv[1], bv[1], bv[1]};
        if (nt == 2) {
#pragma unroll
            for (int ks = 0; ks < KSX; ++ks)
                acc1 = __builtin_amdgcn_mfma_f32_16x16x32_bf16(xc[ks].v, wfrag[1][ks], acc1, 0, 0, 0);
            acc1 = __builtin_amdgcn_mfma_f32_16x16x32_bf16(ah0, wfrag[1][KSX],     acc1, 0, 0, 0);
            acc1 = __builtin_amdgcn_mfma_f32_16x16x32_bf16(ah1, wfrag[1][KSX + 1], acc1, 0, 0, 0);
        }

        {
            int n0 = wv * 16 + ln15;
#pragma unroll
            for (int r = 0; r < 4; ++r) {
                float v = acc0[r];
                zact[lg * 4 + r][n0] = isg[0] ? tanh_(v) : sig_(v);
            }
            if (nt == 2) {
                int n1 = (8 + wv) * 16 + ln15;
#pragma unroll
                for (int r = 0; r < 4; ++r) {
                    float v = acc1[r];
                    zact[lg * 4 + r][n1] = isg[1] ? tanh_(v) : sig_(v);
                }
            }
        }
        __syncthreads();

        // ---- phase B: c/h update ----
        {
            float ig = zact[b0][d0], fg = zact[b0][d0 + DD];
            float gg = zact[b0][d0 + 2 * DD], og = zact[b0][d0 + 3 * DD];
            c0 = fmaf(fg, c0, ig * gg);
            float h = og * tanh_(c0);
            hbuf[b0][d0] = f2b(h);
            out[((long)(btile * MB + b0) * TT + t) * (2 * DD) + dir * DD + d0] = __float2bfloat16(h);
            if (has1) {
                float ig1 = zact[b1][d1], fg1 = zact[b1][d1 + DD];
                float gg1 = zact[b1][d1 + 2 * DD], og1 = zact[b1][d1 + 3 * DD];
                c1 = fmaf(fg1, c1, ig1 * gg1);
                float h1 = og1 * tanh_(c1);
                hbuf[b1][d1] = f2b(h1);
                out[((long)(btile * MB + b1) * TT + t) * (2 * DD) + dir * DD + d1] = __float2bfloat16(h1);
            }
        }
        __syncthreads();

#pragma unroll
        for (int ks = 0; ks < KSX; ++ks)
#pragma unroll
            for (int j = 0; j < 4; ++j) xc[ks].u[j] = xn[ks].u[j];
        t += stp;
    }
}

// ---------------- dense head: per (b,t): 86 -> 30 -> 20 -> 1 ----------------
template <typename TIN>
__global__ void head_kernel(const TIN* __restrict__ h2,
                            const float* __restrict__ w1, const float* __restrict__ b1,
                            const float* __restrict__ w2, const float* __restrict__ b2,
                            const float* __restrict__ w3, const float* __restrict__ b3,
                            float* __restrict__ outp) {
    long bt = (long)blockIdx.x * blockDim.x + threadIdx.x;
    if (bt >= (long)BB * TT) return;
    float v[2 * DD];
    const TIN* src = h2 + bt * (2 * DD);
#pragma unroll
    for (int k = 0; k < 2 * DD; ++k) v[k] = ldv(&src[k]);

    float m1[NH1];
#pragma unroll
    for (int j = 0; j < NH1; ++j) {
        float a = b1[j];
        const float* w = w1 + j * (2 * DD);
#pragma unroll
        for (int k = 0; k < 2 * DD; ++k) a = fmaf(w[k], v[k], a);
        m1[j] = fmaxf(a, 0.0f);
    }
    float m2[NH2];
#pragma unroll
    for (int j = 0; j < NH2; ++j) {
        float a = b2[j];
        const float* w = w2 + j * NH1;
#pragma unroll
        for (int k = 0; k < NH1; ++k) a = fmaf(w[k], m1[k], a);
        m2[j] = fmaxf(a, 0.0f);
    }
    float a = b3[0];
#pragma unroll
    for (int k = 0; k < NH2; ++k) a = fmaf(w3[k], m2[k], a);
    outp[bt] = a;
}

extern "C" void kernel_launch(void* const* d_in, const int* in_sizes, int n_in,
                              void* d_out, int out_size, void* d_ws, size_t ws_size,
                              hipStream_t stream) {
    const float* x      = (const float*)d_in[0];
    const float* w_proj = (const float*)d_in[1];
    const float* b_proj = (const float*)d_in[2];
    const float* w_ih1f = (const float*)d_in[3];
    const float* w_hh1f = (const float*)d_in[4];
    const float* b_ih1f = (const float*)d_in[5];
    const float* b_hh1f = (const float*)d_in[6];
    const float* w_ih1b = (const float*)d_in[7];
    const float* w_hh1b = (const float*)d_in[8];
    const float* b_ih1b = (const float*)d_in[9];
    const float* b_hh1b = (const float*)d_in[10];
    const float* w_ih2f = (const float*)d_in[11];
    const float* w_hh2f = (const float*)d_in[12];
    const float* b_ih2f = (const float*)d_in[13];
    const float* b_hh2f = (const float*)d_in[14];
    const float* w_ih2b = (const float*)d_in[15];
    const float* w_hh2b = (const float*)d_in[16];
    const float* b_ih2b = (const float*)d_in[17];
    const float* b_hh2b = (const float*)d_in[18];
    const float* w_d1   = (const float*)d_in[19];
    const float* b_d1   = (const float*)d_in[20];
    const float* w_d2   = (const float*)d_in[21];
    const float* b_d2   = (const float*)d_in[22];
    const float* w_out  = (const float*)d_in[23];
    const float* b_out  = (const float*)d_in[24];
    (void)in_sizes; (void)n_in; (void)out_size; (void)ws_size;

    // workspace: [W1 | W2 | bias1 | bias2 | (pad to 256KB) | out1 bf16 | out2 bf16]
    char* wsb = (char*)d_ws;
    short* W1    = (short*)(wsb);                       // 2*176*96  shorts = 135168 B
    short* W2    = (short*)(wsb + 135168);              // 2*176*160 shorts = 112640 B
    float* bias1 = (float*)(wsb + 135168 + 112640);     // 352 floats = 1408 B
    float* bias2 = (float*)(wsb + 135168 + 112640 + 1408);
    const size_t o_big = 262144;                        // 256 KB
    const size_t n1    = (size_t)BB * TT * 2 * DD;      // 45,088,768 elems
    bf16* out1 = (bf16*)(wsb + o_big);
    bf16* out2 = (bf16*)(wsb + o_big + n1 * sizeof(bf16));

    {
        const int total = 2 * NPAD * 96 + 2 * NPAD * 160 + 2 * (2 * NPAD);
        prep_kernel<<<(total + 255) / 256, 256, 0, stream>>>(
            w_proj, b_proj,
            w_ih1f, w_hh1f, b_ih1f, b_hh1f, w_ih1b, w_hh1b, b_ih1b, b_hh1b,
            w_ih2f, w_hh2f, b_ih2f, b_hh2f, w_ih2b, w_hh2b, b_ih2b, b_hh2b,
            W1, W2, bias1, bias2);
    }
    // layer 1: x = raw fp32 [B][T][8] (proj folded into W1), out -> out1 bf16
    lstm_mfma<1, true><<<2 * (BB / MB), 512, 0, stream>>>(x, W1, bias1, out1);
    // layer 2: x = out1 bf16 [B][T][86], out -> out2 bf16
    lstm_mfma<3, false><<<2 * (BB / MB), 512, 0, stream>>>(out1, W2, bias2, out2);
    // head
    head_kernel<bf16><<<(int)(((long)BB * TT + 255) / 256), 256, 0, stream>>>(
        out2, w_d1, b_d1, w_d2, b_d2, w_out, b_out, (float*)d_out);
}

// Round 6
// 4643.891 us; speedup vs baseline: 1.2789x; 1.1363x over previous
//
#include <hip/hip_runtime.h>
#include <hip/hip_bf16.h>
#include <math.h>

#define DD   43      // hidden size
#define TT   2048
#define BB   256
#define FEAT 8
#define MB   16      // batches per block (MFMA M)
#define NPAD 192     // 4 gates x 48 padded rows
#define NH1  30
#define NH2  20

using bf16 = __hip_bfloat16;
typedef __attribute__((ext_vector_type(8))) short bf16x8;   // MFMA A/B frag
typedef __attribute__((ext_vector_type(4))) float f32x4;    // MFMA C/D frag

__device__ __forceinline__ float ldv(const float* p) { return *p; }
__device__ __forceinline__ float ldv(const bf16* p)  { return __bfloat162float(*p); }

__device__ __forceinline__ short f2b(float f) {
    bf16 h = __float2bfloat16(f);
    return *reinterpret_cast<short*>(&h);
}
__device__ __forceinline__ float sig_(float x) { return 1.0f / (1.0f + __expf(-x)); }
__device__ __forceinline__ float tanh_(float x) {
    float ax = fabsf(x);
    float e  = __expf(-2.0f * ax);
    float t  = (1.0f - e) / (1.0f + e);
    return x < 0.0f ? -t : t;
}
__device__ __forceinline__ bf16x8 mk8(const unsigned u[4]) {
    union { unsigned u[4]; bf16x8 v; } x;
    x.u[0] = u[0]; x.u[1] = u[1]; x.u[2] = u[2]; x.u[3] = u[3];
    return x.v;
}

// ---------------- prep: gate-padded bf16 weight blocks + combined fp32 biases ----
// Row n in [0,192): gate q = n/48, dq = n%48, original row = q*43+dq (dq<43, else 0).
// W1 [2][192][96] : k<8 = w_ih1 @ w_proj (proj folded), k in [32,75) = w_hh1, else 0.
// W2 [2][192][160]: k<86 = w_ih2, k in [96,139) = w_hh2, else 0.
// bias1[2][192] = b_ih1+b_hh1 + w_ih1@b_proj ; bias2[2][192] = b_ih2+b_hh2.
__global__ void prep_kernel(
    const float* __restrict__ wp, const float* __restrict__ bp,
    const float* __restrict__ w_ih1f, const float* __restrict__ w_hh1f,
    const float* __restrict__ b_ih1f, const float* __restrict__ b_hh1f,
    const float* __restrict__ w_ih1b, const float* __restrict__ w_hh1b,
    const float* __restrict__ b_ih1b, const float* __restrict__ b_hh1b,
    const float* __restrict__ w_ih2f, const float* __restrict__ w_hh2f,
    const float* __restrict__ b_ih2f, const float* __restrict__ b_hh2f,
    const float* __restrict__ w_ih2b, const float* __restrict__ w_hh2b,
    const float* __restrict__ b_ih2b, const float* __restrict__ b_hh2b,
    short* __restrict__ W1, short* __restrict__ W2,
    float* __restrict__ bias1, float* __restrict__ bias2)
{
    const int KP1 = 96, KP2 = 160;
    const int S1 = 2 * NPAD * KP1, S2 = 2 * NPAD * KP2, S3 = 2 * NPAD;
    int idx = blockIdx.x * blockDim.x + threadIdx.x;
    if (idx < S1) {
        int dir = idx / (NPAD * KP1), rem = idx % (NPAD * KP1);
        int n = rem / KP1, k = rem % KP1;
        int q = n / 48, dq = n % 48;
        float v = 0.0f;
        if (dq < DD) {
            int orig = q * DD + dq;
            const float* wih = dir ? w_ih1b : w_ih1f;
            const float* whh = dir ? w_hh1b : w_hh1f;
            if (k < FEAT) {
                for (int d = 0; d < DD; ++d) v = fmaf(wih[orig * DD + d], wp[d * FEAT + k], v);
            } else if (k >= 32 && k < 32 + DD) {
                v = whh[orig * DD + (k - 32)];
            }
        }
        W1[idx] = f2b(v);
    } else if (idx < S1 + S2) {
        int j = idx - S1;
        int dir = j / (NPAD * KP2), rem = j % (NPAD * KP2);
        int n = rem / KP2, k = rem % KP2;
        int q = n / 48, dq = n % 48;
        float v = 0.0f;
        if (dq < DD) {
            int orig = q * DD + dq;
            const float* wih = dir ? w_ih2b : w_ih2f;
            const float* whh = dir ? w_hh2b : w_hh2f;
            if (k < 2 * DD)                  v = wih[orig * (2 * DD) + k];
            else if (k >= 96 && k < 96 + DD) v = whh[orig * DD + (k - 96)];
        }
        W2[j] = f2b(v);
    } else if (idx < S1 + S2 + S3) {
        int j = idx - S1 - S2;
        int dir = j / NPAD, n = j % NPAD;
        int q = n / 48, dq = n % 48;
        float v = 0.0f;
        if (dq < DD) {
            int orig = q * DD + dq;
            const float* wih = dir ? w_ih1b : w_ih1f;
            const float* bi  = dir ? b_ih1b : b_ih1f;
            const float* bh  = dir ? b_hh1b : b_hh1f;
            v = bi[orig] + bh[orig];
            for (int d = 0; d < DD; ++d) v = fmaf(wih[orig * DD + d], bp[d], v);
        }
        bias1[j] = v;
    } else if (idx < S1 + S2 + 2 * S3) {
        int j = idx - S1 - S2 - S3;
        int dir = j / NPAD, n = j % NPAD;
        int q = n / 48, dq = n % 48;
        float v = 0.0f;
        if (dq < DD) {
            int orig = q * DD + dq;
            const float* bi = dir ? b_ih2b : b_ih2f;
            const float* bh = dir ? b_hh2b : b_hh2f;
            v = bi[orig] + bh[orig];
        }
        bias2[j] = v;
    }
}

// ---------------- MFMA BiLSTM layer, gate-aligned, 3 waves, 1 barrier/step ----
// Block = (dir, 16-batch tile); 192 threads. Wave w owns n-tiles {w, w+3, w+6, w+9}
// = gates i,f,g,o for d = w*16 + (lane&15). C layout (col=lane&15=d, row=batch)
// makes the c/h update lane-local: no transpose LDS, no second barrier.
template <int KSX, bool XRAW>
__global__ __launch_bounds__(192)
__attribute__((amdgpu_waves_per_eu(1)))
void lstm_mfma(
    const void*  __restrict__ in_,     // XRAW ? fp32 [B][T][8] : bf16 [B][T][86]
    const short* __restrict__ Wb,      // [2][NPAD][KPAD] bf16 bits
    const float* __restrict__ bias,    // [2][NPAD]
    bf16* __restrict__ out)            // [B][T][86]; fills cols dir*43 .. +43
{
    constexpr int KS   = KSX + 2;      // x K-steps + 2 for h (43 -> 64 pad)
    constexpr int KPAD = KS * 32;

    const int dir   = blockIdx.x & 1;
    const int btile = blockIdx.x >> 1;
    const int tid   = threadIdx.x;
    const int lane  = tid & 63;
    const int wv    = tid >> 6;        // 0..2
    const int ln15  = lane & 15;
    const int lg    = lane >> 4;       // 0..3

    __shared__ __align__(16) short hbuf[2][MB][72];  // bf16 h (double-buffered), cols 43..63 = 0

    const int  dq   = wv * 16 + ln15;  // 0..47, valid < 43
    const bool dval = dq < DD;

    // weight fragments: 4 gates x KS k-steps, pinned in VGPRs (asm identity
    // blocks the allocator's load-rematerialization seen in rounds 3-5)
    unsigned wf[4][KS][4];
    float bv[4];
    {
        const short* Wd = Wb + (size_t)dir * NPAD * KPAD;
#pragma unroll
        for (int q = 0; q < 4; ++q) {
            const short* row = Wd + (size_t)(q * 48 + dq) * KPAD;
#pragma unroll
            for (int ks = 0; ks < KS; ++ks) {
                const unsigned* p = reinterpret_cast<const unsigned*>(row + ks * 32 + lg * 8);
#pragma unroll
                for (int j = 0; j < 4; ++j) wf[q][ks][j] = p[j];
                asm volatile("" : "+v"(wf[q][ks][0]), "+v"(wf[q][ks][1]),
                                  "+v"(wf[q][ks][2]), "+v"(wf[q][ks][3]));
            }
            bv[q] = bias[dir * NPAD + q * 48 + dq];
        }
        asm volatile("" : "+v"(bv[0]), "+v"(bv[1]), "+v"(bv[2]), "+v"(bv[3]));
    }

    for (int i = tid; i < 2 * MB * 72; i += 192) ((short*)hbuf)[i] = 0;

    const long t0  = dir ? (TT - 1) : 0;
    const int  stp = dir ? -1 : 1;
    const int  bb  = btile * MB + ln15;          // batch this lane feeds into A-frags

    unsigned xe[KSX][4], xo[KSX][4];
    auto load_x = [&](long t, unsigned (&xf)[KSX][4]) {
        long tc = t < 0 ? 0 : (t >= TT ? TT - 1 : t);
        if constexpr (XRAW) {
            if (lg == 0) {
                const float* xp = (const float*)in_ + ((long)bb * TT + tc) * FEAT;
                float4 v0 = *reinterpret_cast<const float4*>(xp);
                float4 v1 = *reinterpret_cast<const float4*>(xp + 4);
                xf[0][0] = ((unsigned)(unsigned short)f2b(v0.y) << 16) | (unsigned short)f2b(v0.x);
                xf[0][1] = ((unsigned)(unsigned short)f2b(v0.w) << 16) | (unsigned short)f2b(v0.z);
                xf[0][2] = ((unsigned)(unsigned short)f2b(v1.y) << 16) | (unsigned short)f2b(v1.x);
                xf[0][3] = ((unsigned)(unsigned short)f2b(v1.w) << 16) | (unsigned short)f2b(v1.z);
            } else {
#pragma unroll
                for (int j = 0; j < 4; ++j) xf[0][j] = 0u;
            }
        } else {
            const short* xp = (const short*)in_ + ((long)bb * TT + tc) * (2 * DD);
#pragma unroll
            for (int ks = 0; ks < KSX; ++ks)
#pragma unroll
                for (int j = 0; j < 4; ++j) {
                    int k = ks * 32 + lg * 8 + 2 * j;
                    xf[ks][j] = (k < 2 * DD) ? *reinterpret_cast<const unsigned*>(xp + k) : 0u;
                }
        }
    };

    float cc[4] = {0.0f, 0.0f, 0.0f, 0.0f};

    load_x(t0, xe);
    load_x(t0 + stp, xo);
    __syncthreads();   // hbuf zeros visible (full drain OK once)

    auto step = [&](unsigned (&xf)[KSX][4], int s, long t) {
        bf16x8 ah0 = *reinterpret_cast<const bf16x8*>(&hbuf[s & 1][ln15][lg * 8]);
        bf16x8 ah1 = *reinterpret_cast<const bf16x8*>(&hbuf[s & 1][ln15][32 + lg * 8]);

        f32x4 acc[4];
#pragma unroll
        for (int q = 0; q < 4; ++q) acc[q] = (f32x4){bv[q], bv[q], bv[q], bv[q]};
#pragma unroll
        for (int ks = 0; ks < KSX; ++ks) {
            bf16x8 av = mk8(xf[ks]);
#pragma unroll
            for (int q = 0; q < 4; ++q)
                acc[q] = __builtin_amdgcn_mfma_f32_16x16x32_bf16(av, mk8(wf[q][ks]), acc[q], 0, 0, 0);
        }
#pragma unroll
        for (int q = 0; q < 4; ++q)
            acc[q] = __builtin_amdgcn_mfma_f32_16x16x32_bf16(ah0, mk8(wf[q][KSX]), acc[q], 0, 0, 0);
#pragma unroll
        for (int q = 0; q < 4; ++q)
            acc[q] = __builtin_amdgcn_mfma_f32_16x16x32_bf16(ah1, mk8(wf[q][KSX + 1]), acc[q], 0, 0, 0);

        load_x(t + 2 * stp, xf);   // prefetch 2 steps ahead; floats across raw barriers

        // lane-local i/f/g/o -> c/h for 4 batches at this lane's d
#pragma unroll
        for (int r = 0; r < 4; ++r) {
            float ig = sig_(acc[0][r]);
            float fg = sig_(acc[1][r]);
            float gg = tanh_(acc[2][r]);
            float og = sig_(acc[3][r]);
            cc[r] = fmaf(fg, cc[r], ig * gg);
            float h = og * tanh_(cc[r]);
            if (dval) {
                hbuf[(s + 1) & 1][lg * 4 + r][dq] = f2b(h);
                out[((long)(btile * MB + lg * 4 + r) * TT + t) * (2 * DD) + dir * DD + dq] =
                    __float2bfloat16(h);
            }
        }
        // raw barrier: wait LDS only -- vmem prefetch/out-stores stay in flight
        asm volatile("s_waitcnt lgkmcnt(0)" ::: "memory");
        __builtin_amdgcn_sched_barrier(0);
        __builtin_amdgcn_s_barrier();
    };

    long t = t0;
    for (int s = 0; s < TT; s += 2) {
        step(xe, s, t);     t += stp;
        step(xo, s + 1, t); t += stp;
    }
}

// ---------------- dense head: per (b,t): 86 -> 30 -> 20 -> 1 ----------------
template <typename TIN>
__global__ void head_kernel(const TIN* __restrict__ h2,
                            const float* __restrict__ w1, const float* __restrict__ b1,
                            const float* __restrict__ w2, const float* __restrict__ b2,
                            const float* __restrict__ w3, const float* __restrict__ b3,
                            float* __restrict__ outp) {
    long bt = (long)blockIdx.x * blockDim.x + threadIdx.x;
    if (bt >= (long)BB * TT) return;
    float v[2 * DD];
    const TIN* src = h2 + bt * (2 * DD);
#pragma unroll
    for (int k = 0; k < 2 * DD; ++k) v[k] = ldv(&src[k]);

    float m1[NH1];
#pragma unroll
    for (int j = 0; j < NH1; ++j) {
        float a = b1[j];
        const float* w = w1 + j * (2 * DD);
#pragma unroll
        for (int k = 0; k < 2 * DD; ++k) a = fmaf(w[k], v[k], a);
        m1[j] = fmaxf(a, 0.0f);
    }
    float m2[NH2];
#pragma unroll
    for (int j = 0; j < NH2; ++j) {
        float a = b2[j];
        const float* w = w2 + j * NH1;
#pragma unroll
        for (int k = 0; k < NH1; ++k) a = fmaf(w[k], m1[k], a);
        m2[j] = fmaxf(a, 0.0f);
    }
    float a = b3[0];
#pragma unroll
    for (int k = 0; k < NH2; ++k) a = fmaf(w3[k], m2[k], a);
    outp[bt] = a;
}

extern "C" void kernel_launch(void* const* d_in, const int* in_sizes, int n_in,
                              void* d_out, int out_size, void* d_ws, size_t ws_size,
                              hipStream_t stream) {
    const float* x      = (const float*)d_in[0];
    const float* w_proj = (const float*)d_in[1];
    const float* b_proj = (const float*)d_in[2];
    const float* w_ih1f = (const float*)d_in[3];
    const float* w_hh1f = (const float*)d_in[4];
    const float* b_ih1f = (const float*)d_in[5];
    const float* b_hh1f = (const float*)d_in[6];
    const float* w_ih1b = (const float*)d_in[7];
    const float* w_hh1b = (const float*)d_in[8];
    const float* b_ih1b = (const float*)d_in[9];
    const float* b_hh1b = (const float*)d_in[10];
    const float* w_ih2f = (const float*)d_in[11];
    const float* w_hh2f = (const float*)d_in[12];
    const float* b_ih2f = (const float*)d_in[13];
    const float* b_hh2f = (const float*)d_in[14];
    const float* w_ih2b = (const float*)d_in[15];
    const float* w_hh2b = (const float*)d_in[16];
    const float* b_ih2b = (const float*)d_in[17];
    const float* b_hh2b = (const float*)d_in[18];
    const float* w_d1   = (const float*)d_in[19];
    const float* b_d1   = (const float*)d_in[20];
    const float* w_d2   = (const float*)d_in[21];
    const float* b_d2   = (const float*)d_in[22];
    const float* w_out  = (const float*)d_in[23];
    const float* b_out  = (const float*)d_in[24];
    (void)in_sizes; (void)n_in; (void)out_size; (void)ws_size;

    // workspace: [W1 | W2 | bias1 | bias2 | pad->256KB | out1 bf16 | out2 bf16]
    char* wsb = (char*)d_ws;
    short* W1    = (short*)(wsb);                         // 2*192*96*2  = 73728 B
    short* W2    = (short*)(wsb + 73728);                 // 2*192*160*2 = 122880 B
    float* bias1 = (float*)(wsb + 73728 + 122880);        // 1536 B
    float* bias2 = (float*)(wsb + 73728 + 122880 + 1536);
    const size_t o_big = 262144;
    const size_t n1    = (size_t)BB * TT * 2 * DD;        // 45,088,768 elems
    bf16* out1 = (bf16*)(wsb + o_big);
    bf16* out2 = (bf16*)(wsb + o_big + n1 * sizeof(bf16));

    {
        const int total = 2 * NPAD * 96 + 2 * NPAD * 160 + 2 * (2 * NPAD);
        prep_kernel<<<(total + 255) / 256, 256, 0, stream>>>(
            w_proj, b_proj,
            w_ih1f, w_hh1f, b_ih1f, b_hh1f, w_ih1b, w_hh1b, b_ih1b, b_hh1b,
            w_ih2f, w_hh2f, b_ih2f, b_hh2f, w_ih2b, w_hh2b, b_ih2b, b_hh2b,
            W1, W2, bias1, bias2);
    }
    // layer 1: raw fp32 x (proj folded), KSX=1
    lstm_mfma<1, true><<<2 * (BB / MB), 192, 0, stream>>>(x, W1, bias1, out1);
    // layer 2: bf16 out1, KSX=3
    lstm_mfma<3, false><<<2 * (BB / MB), 192, 0, stream>>>(out1, W2, bias2, out2);
    // head
    head_kernel<bf16><<<(int)(((long)BB * TT + 255) / 256), 256, 0, stream>>>(
        out2, w_d1, b_d1, w_d2, b_d2, w_out, b_out, (float*)d_out);
}

// Round 7
// 3616.214 us; speedup vs baseline: 1.6424x; 1.2842x over previous
//
#include <hip/hip_runtime.h>
#include <hip/hip_bf16.h>
#include <math.h>

#define DD   43      // hidden size
#define TT   2048
#define BB   256
#define FEAT 8
#define MB   16      // batches per block (MFMA M)
#define NPAD 192     // 4 gates x 48 padded rows
#define NH1  30
#define NH2  20

using bf16 = __hip_bfloat16;
typedef __attribute__((ext_vector_type(8))) short bf16x8;   // MFMA A frag
typedef __attribute__((ext_vector_type(4))) int   i32x4;    // MFMA B frag (AGPR)
typedef __attribute__((ext_vector_type(4))) float f32x4;    // MFMA C/D frag

__device__ __forceinline__ float ldv(const float* p) { return *p; }
__device__ __forceinline__ float ldv(const bf16* p)  { return __bfloat162float(*p); }

__device__ __forceinline__ short f2b(float f) {
    bf16 h = __float2bfloat16(f);
    return *reinterpret_cast<short*>(&h);
}
#define LOG2E 1.44269504f
__device__ __forceinline__ float sig_(float x) {
    return __builtin_amdgcn_rcpf(1.0f + __builtin_amdgcn_exp2f(-LOG2E * x));
}
__device__ __forceinline__ float tanh_(float x) {
    // tanh(x) = 1 - 2/(1+e^{2x}); monotone-safe at +-inf
    return fmaf(-2.0f, __builtin_amdgcn_rcpf(1.0f + __builtin_amdgcn_exp2f(2.0f * LOG2E * x)), 1.0f);
}
__device__ __forceinline__ bf16x8 mk8(const unsigned u[4]) {
    union { unsigned u[4]; bf16x8 v; } x;
    x.u[0] = u[0]; x.u[1] = u[1]; x.u[2] = u[2]; x.u[3] = u[3];
    return x.v;
}
// MFMA with B operand pinned to AGPR class ("a") -- weights live in the AGPR
// file for the kernel lifetime; VGPR allocator never sees their pressure.
__device__ __forceinline__ void mfma_a(f32x4& d, bf16x8 a, i32x4 b) {
    asm("v_mfma_f32_16x16x32_bf16 %0, %1, %2, %0" : "+v"(d) : "v"(a), "a"(b));
}

// ---------------- prep: gate-padded bf16 weight blocks + combined fp32 biases ----
// Row n in [0,192): gate q = n/48, dq = n%48, original row = q*43+dq (dq<43, else 0).
// W1 [2][192][96] : k<8 = w_ih1 @ w_proj (proj folded), k in [32,75) = w_hh1, else 0.
// W2 [2][192][160]: k<86 = w_ih2, k in [96,139) = w_hh2, else 0.
// bias1[2][192] = b_ih1+b_hh1 + w_ih1@b_proj ; bias2[2][192] = b_ih2+b_hh2.
__global__ void prep_kernel(
    const float* __restrict__ wp, const float* __restrict__ bp,
    const float* __restrict__ w_ih1f, const float* __restrict__ w_hh1f,
    const float* __restrict__ b_ih1f, const float* __restrict__ b_hh1f,
    const float* __restrict__ w_ih1b, const float* __restrict__ w_hh1b,
    const float* __restrict__ b_ih1b, const float* __restrict__ b_hh1b,
    const float* __restrict__ w_ih2f, const float* __restrict__ w_hh2f,
    const float* __restrict__ b_ih2f, const float* __restrict__ b_hh2f,
    const float* __restrict__ w_ih2b, const float* __restrict__ w_hh2b,
    const float* __restrict__ b_ih2b, const float* __restrict__ b_hh2b,
    short* __restrict__ W1, short* __restrict__ W2,
    float* __restrict__ bias1, float* __restrict__ bias2)
{
    const int KP1 = 96, KP2 = 160;
    const int S1 = 2 * NPAD * KP1, S2 = 2 * NPAD * KP2, S3 = 2 * NPAD;
    int idx = blockIdx.x * blockDim.x + threadIdx.x;
    if (idx < S1) {
        int dir = idx / (NPAD * KP1), rem = idx % (NPAD * KP1);
        int n = rem / KP1, k = rem % KP1;
        int q = n / 48, dq = n % 48;
        float v = 0.0f;
        if (dq < DD) {
            int orig = q * DD + dq;
            const float* wih = dir ? w_ih1b : w_ih1f;
            const float* whh = dir ? w_hh1b : w_hh1f;
            if (k < FEAT) {
                for (int d = 0; d < DD; ++d) v = fmaf(wih[orig * DD + d], wp[d * FEAT + k], v);
            } else if (k >= 32 && k < 32 + DD) {
                v = whh[orig * DD + (k - 32)];
            }
        }
        W1[idx] = f2b(v);
    } else if (idx < S1 + S2) {
        int j = idx - S1;
        int dir = j / (NPAD * KP2), rem = j % (NPAD * KP2);
        int n = rem / KP2, k = rem % KP2;
        int q = n / 48, dq = n % 48;
        float v = 0.0f;
        if (dq < DD) {
            int orig = q * DD + dq;
            const float* wih = dir ? w_ih2b : w_ih2f;
            const float* whh = dir ? w_hh2b : w_hh2f;
            if (k < 2 * DD)                  v = wih[orig * (2 * DD) + k];
            else if (k >= 96 && k < 96 + DD) v = whh[orig * DD + (k - 96)];
        }
        W2[j] = f2b(v);
    } else if (idx < S1 + S2 + S3) {
        int j = idx - S1 - S2;
        int dir = j / NPAD, n = j % NPAD;
        int q = n / 48, dq = n % 48;
        float v = 0.0f;
        if (dq < DD) {
            int orig = q * DD + dq;
            const float* wih = dir ? w_ih1b : w_ih1f;
            const float* bi  = dir ? b_ih1b : b_ih1f;
            const float* bh  = dir ? b_hh1b : b_hh1f;
            v = bi[orig] + bh[orig];
            for (int d = 0; d < DD; ++d) v = fmaf(wih[orig * DD + d], bp[d], v);
        }
        bias1[j] = v;
    } else if (idx < S1 + S2 + 2 * S3) {
        int j = idx - S1 - S2 - S3;
        int dir = j / NPAD, n = j % NPAD;
        int q = n / 48, dq = n % 48;
        float v = 0.0f;
        if (dq < DD) {
            int orig = q * DD + dq;
            const float* bi = dir ? b_ih2b : b_ih2f;
            const float* bh = dir ? b_hh2b : b_hh2f;
            v = bi[orig] + bh[orig];
        }
        bias2[j] = v;
    }
}

// ---------------- MFMA BiLSTM layer, gate-aligned, 3 waves, 1 barrier/step ----
// Block = (dir, 16-batch tile); 192 threads. Wave w owns gates i,f,g,o for
// d = w*16 + (lane&15) (rows q*48+d of the padded W). C layout (col=lane&15=d,
// row=batch) makes the c/h update lane-local. Weights are AGPR-resident
// (mfma_a). x-part GEMM for step s+1 is issued pre-barrier into a ping-ponged
// xacc, overlapping the activation VALU (separate pipes).
template <int KSX, bool XRAW>
__global__ __launch_bounds__(192, 1)   // min 1 wave/EU -> 512-VGPR allocator budget
void lstm_mfma(
    const void*  __restrict__ in_,     // XRAW ? fp32 [B][T][8] : bf16 [B][T][86]
    const short* __restrict__ Wb,      // [2][NPAD][KPAD] bf16 bits
    const float* __restrict__ bias,    // [2][NPAD]
    bf16* __restrict__ out)            // [B][T][86]; fills cols dir*43 .. +43
{
    constexpr int KS   = KSX + 2;      // x K-steps + 2 for h (43 -> 64 pad)
    constexpr int KPAD = KS * 32;

    const int dir   = blockIdx.x & 1;
    const int btile = blockIdx.x >> 1;
    const int tid   = threadIdx.x;
    const int lane  = tid & 63;
    const int wv    = tid >> 6;        // 0..2
    const int ln15  = lane & 15;
    const int lg    = lane >> 4;       // 0..3

    __shared__ __align__(16) short hbuf[2][MB][72];  // bf16 h (dbuf), cols 43..63 = 0

    const int  dq   = wv * 16 + ln15;  // 0..47, valid < 43
    const bool dval = dq < DD;

    // ---- weights -> AGPRs (loaded once; "+a" def blocks rematerialization) ----
    i32x4 wx[4][KSX];
    i32x4 wh[4][2];
    float bv[4];
    {
        const short* Wd = Wb + (size_t)dir * NPAD * KPAD;
#pragma unroll
        for (int q = 0; q < 4; ++q) {
            const short* row = Wd + (size_t)(q * 48 + dq) * KPAD;
#pragma unroll
            for (int ks = 0; ks < KSX; ++ks)
                wx[q][ks] = *reinterpret_cast<const i32x4*>(row + ks * 32 + lg * 8);
            wh[q][0] = *reinterpret_cast<const i32x4*>(row + KSX * 32 + lg * 8);
            wh[q][1] = *reinterpret_cast<const i32x4*>(row + (KSX + 1) * 32 + lg * 8);
            bv[q] = bias[dir * NPAD + q * 48 + dq];
        }
#pragma unroll
        for (int q = 0; q < 4; ++q) {
#pragma unroll
            for (int ks = 0; ks < KSX; ++ks)
                asm volatile("" : "+a"(wx[q][ks]));
            asm volatile("" : "+a"(wh[q][0]), "+a"(wh[q][1]));
        }
    }

    for (int i = tid; i < 2 * MB * 72; i += 192) ((short*)hbuf)[i] = 0;

    const long t0  = dir ? (TT - 1) : 0;
    const int  stp = dir ? -1 : 1;
    const int  bb  = btile * MB + ln15;          // batch this lane feeds into A-frags

    unsigned xe[KSX][4], xo[KSX][4];
    auto load_x = [&](long t, unsigned (&xf)[KSX][4]) {
        long tc = t < 0 ? 0 : (t >= TT ? TT - 1 : t);
        if constexpr (XRAW) {
            if (lg == 0) {
                const float* xp = (const float*)in_ + ((long)bb * TT + tc) * FEAT;
                float4 v0 = *reinterpret_cast<const float4*>(xp);
                float4 v1 = *reinterpret_cast<const float4*>(xp + 4);
                xf[0][0] = ((unsigned)(unsigned short)f2b(v0.y) << 16) | (unsigned short)f2b(v0.x);
                xf[0][1] = ((unsigned)(unsigned short)f2b(v0.w) << 16) | (unsigned short)f2b(v0.z);
                xf[0][2] = ((unsigned)(unsigned short)f2b(v1.y) << 16) | (unsigned short)f2b(v1.x);
                xf[0][3] = ((unsigned)(unsigned short)f2b(v1.w) << 16) | (unsigned short)f2b(v1.z);
            } else {
#pragma unroll
                for (int j = 0; j < 4; ++j) xf[0][j] = 0u;
            }
        } else {
            const short* xp = (const short*)in_ + ((long)bb * TT + tc) * (2 * DD);
#pragma unroll
            for (int ks = 0; ks < KSX; ++ks)
#pragma unroll
                for (int j = 0; j < 4; ++j) {
                    int k = ks * 32 + lg * 8 + 2 * j;
                    xf[ks][j] = (k < 2 * DD) ? *reinterpret_cast<const unsigned*>(xp + k) : 0u;
                }
        }
    };

    // xacc = bias + W_x . x(t)  (off the h-critical path)
    auto xinit = [&](unsigned (&xf)[KSX][4], f32x4 (&xa)[4]) {
#pragma unroll
        for (int q = 0; q < 4; ++q) {
            f32x4 a = {bv[q], bv[q], bv[q], bv[q]};
#pragma unroll
            for (int ks = 0; ks < KSX; ++ks)
                mfma_a(a, mk8(xf[ks]), wx[q][ks]);
            xa[q] = a;
        }
    };

    float cc[4] = {0.0f, 0.0f, 0.0f, 0.0f};
    f32x4 xaccE[4], xaccO[4];

    load_x(t0, xe);
    load_x(t0 + stp, xo);
    __syncthreads();            // hbuf zeros visible (full drain OK once)
    xinit(xe, xaccE);           // xacc for step 0

    // one timestep: finish z with h-MFMAs, prefetch x(t+2), start next xacc
    // (overlaps activations on the VALU pipe), then activations + state update.
    auto step = [&](unsigned (&cur)[KSX][4], unsigned (&oth)[KSX][4],
                    f32x4 (&accC)[4], f32x4 (&accN)[4], int par, long t) {
        bf16x8 ah0 = *reinterpret_cast<const bf16x8*>(&hbuf[par][ln15][lg * 8]);
        bf16x8 ah1 = *reinterpret_cast<const bf16x8*>(&hbuf[par][ln15][32 + lg * 8]);
#pragma unroll
        for (int q = 0; q < 4; ++q) {
            mfma_a(accC[q], ah0, wh[q][0]);
            mfma_a(accC[q], ah1, wh[q][1]);
        }
        load_x(t + 2 * stp, cur);     // prefetch 2 steps ahead (floats across barrier)
        xinit(oth, accN);             // next step's x-part (MFMA pipe, overlaps acts)

#pragma unroll
        for (int r = 0; r < 4; ++r) {
            float ig = sig_(accC[0][r]);
            float fg = sig_(accC[1][r]);
            float gg = tanh_(accC[2][r]);
            float og = sig_(accC[3][r]);
            cc[r] = fmaf(fg, cc[r], ig * gg);
            float h = og * tanh_(cc[r]);
            if (dval) {
                hbuf[par ^ 1][lg * 4 + r][dq] = f2b(h);
                out[((long)(btile * MB + lg * 4 + r) * TT + t) * (2 * DD) + dir * DD + dq] =
                    __float2bfloat16(h);
            }
        }
        // barrier waits LDS only -- vmem prefetch / out-stores stay in flight
        asm volatile("s_waitcnt lgkmcnt(0)" ::: "memory");
        __builtin_amdgcn_sched_barrier(0);
        __builtin_amdgcn_s_barrier();
    };

    long t = t0;
    for (int s = 0; s < TT; s += 2) {
        step(xe, xo, xaccE, xaccO, 0, t); t += stp;
        step(xo, xe, xaccO, xaccE, 1, t); t += stp;
    }
}

// ---------------- dense head: per (b,t): 86 -> 30 -> 20 -> 1 ----------------
template <typename TIN>
__global__ void head_kernel(const TIN* __restrict__ h2,
                            const float* __restrict__ w1, const float* __restrict__ b1,
                            const float* __restrict__ w2, const float* __restrict__ b2,
                            const float* __restrict__ w3, const float* __restrict__ b3,
                            float* __restrict__ outp) {
    long bt = (long)blockIdx.x * blockDim.x + threadIdx.x;
    if (bt >= (long)BB * TT) return;
    float v[2 * DD];
    const TIN* src = h2 + bt * (2 * DD);
#pragma unroll
    for (int k = 0; k < 2 * DD; ++k) v[k] = ldv(&src[k]);

    float m1[NH1];
#pragma unroll
    for (int j = 0; j < NH1; ++j) {
        float a = b1[j];
        const float* w = w1 + j * (2 * DD);
#pragma unroll
        for (int k = 0; k < 2 * DD; ++k) a = fmaf(w[k], v[k], a);
        m1[j] = fmaxf(a, 0.0f);
    }
    float m2[NH2];
#pragma unroll
    for (int j = 0; j < NH2; ++j) {
        float a = b2[j];
        const float* w = w2 + j * NH1;
#pragma unroll
        for (int k = 0; k < NH1; ++k) a = fmaf(w[k], m1[k], a);
        m2[j] = fmaxf(a, 0.0f);
    }
    float a = b3[0];
#pragma unroll
    for (int k = 0; k < NH2; ++k) a = fmaf(w3[k], m2[k], a);
    outp[bt] = a;
}

extern "C" void kernel_launch(void* const* d_in, const int* in_sizes, int n_in,
                              void* d_out, int out_size, void* d_ws, size_t ws_size,
                              hipStream_t stream) {
    const float* x      = (const float*)d_in[0];
    const float* w_proj = (const float*)d_in[1];
    const float* b_proj = (const float*)d_in[2];
    const float* w_ih1f = (const float*)d_in[3];
    const float* w_hh1f = (const float*)d_in[4];
    const float* b_ih1f = (const float*)d_in[5];
    const float* b_hh1f = (const float*)d_in[6];
    const float* w_ih1b = (const float*)d_in[7];
    const float* w_hh1b = (const float*)d_in[8];
    const float* b_ih1b = (const float*)d_in[9];
    const float* b_hh1b = (const float*)d_in[10];
    const float* w_ih2f = (const float*)d_in[11];
    const float* w_hh2f = (const float*)d_in[12];
    const float* b_ih2f = (const float*)d_in[13];
    const float* b_hh2f = (const float*)d_in[14];
    const float* w_ih2b = (const float*)d_in[15];
    const float* w_hh2b = (const float*)d_in[16];
    const float* b_ih2b = (const float*)d_in[17];
    const float* b_hh2b = (const float*)d_in[18];
    const float* w_d1   = (const float*)d_in[19];
    const float* b_d1   = (const float*)d_in[20];
    const float* w_d2   = (const float*)d_in[21];
    const float* b_d2   = (const float*)d_in[22];
    const float* w_out  = (const float*)d_in[23];
    const float* b_out  = (const float*)d_in[24];
    (void)in_sizes; (void)n_in; (void)out_size; (void)ws_size;

    // workspace: [W1 | W2 | bias1 | bias2 | pad->256KB | out1 bf16 | out2 bf16]
    char* wsb = (char*)d_ws;
    short* W1    = (short*)(wsb);                         // 2*192*96*2  = 73728 B
    short* W2    = (short*)(wsb + 73728);                 // 2*192*160*2 = 122880 B
    float* bias1 = (float*)(wsb + 73728 + 122880);        // 1536 B
    float* bias2 = (float*)(wsb + 73728 + 122880 + 1536);
    const size_t o_big = 262144;
    const size_t n1    = (size_t)BB * TT * 2 * DD;        // 45,088,768 elems
    bf16* out1 = (bf16*)(wsb + o_big);
    bf16* out2 = (bf16*)(wsb + o_big + n1 * sizeof(bf16));

    {
        const int total = 2 * NPAD * 96 + 2 * NPAD * 160 + 2 * (2 * NPAD);
        prep_kernel<<<(total + 255) / 256, 256, 0, stream>>>(
            w_proj, b_proj,
            w_ih1f, w_hh1f, b_ih1f, b_hh1f, w_ih1b, w_hh1b, b_ih1b, b_hh1b,
            w_ih2f, w_hh2f, b_ih2f, b_hh2f, w_ih2b, w_hh2b, b_ih2b, b_hh2b,
            W1, W2, bias1, bias2);
    }
    // layer 1: raw fp32 x (proj folded), KSX=1
    lstm_mfma<1, true><<<2 * (BB / MB), 192, 0, stream>>>(x, W1, bias1, out1);
    // layer 2: bf16 out1, KSX=3
    lstm_mfma<3, false><<<2 * (BB / MB), 192, 0, stream>>>(out1, W2, bias2, out2);
    // head
    head_kernel<bf16><<<(int)(((long)BB * TT + 255) / 256), 256, 0, stream>>>(
        out2, w_d1, b_d1, w_d2, b_d2, w_out, b_out, (float*)d_out);
}